// Round 7
// baseline (266.405 us; speedup 1.0000x reference)
//
#include <hip/hip_runtime.h>

typedef __attribute__((ext_vector_type(4))) float f32x4;
typedef __attribute__((ext_vector_type(8))) short s16x8;
typedef __attribute__((ext_vector_type(8))) __bf16 bf16x8;
typedef unsigned short u16;

__device__ __forceinline__ u16 f2b(float f) {
  union { float f; unsigned u; } x; x.f = f;
  unsigned r = x.u + 0x7fffu + ((x.u >> 16) & 1u);
  return (u16)(r >> 16);
}
__device__ __forceinline__ float b2f(u16 u) {
  union { unsigned u; float f; } x; x.u = ((unsigned)u) << 16;
  return x.f;
}
__device__ __forceinline__ void gld16(const void* g, void* l) {
  __builtin_amdgcn_global_load_lds(
      (const __attribute__((address_space(1))) unsigned int*)g,
      (__attribute__((address_space(3))) unsigned int*)l, 16, 0, 0);
}
__device__ __forceinline__ f32x4 mfma_bf16(s16x8 a, s16x8 b, f32x4 c) {
  return __builtin_amdgcn_mfma_f32_16x16x32_bf16(
      __builtin_bit_cast(bf16x8, a), __builtin_bit_cast(bf16x8, b), c, 0, 0, 0);
}

#define BAR() asm volatile("s_barrier" ::: "memory")

// ---------------- fused fp32->bf16 conversion (all three activations) ----------------
__global__ void k_convert_all(const float* __restrict__ hs, const float* __restrict__ ehs,
                              const float* __restrict__ iph,
                              u16* __restrict__ hsb, u16* __restrict__ ehsb,
                              u16* __restrict__ ipb) {
  const int n1 = 16384 * 1280 / 4, n2 = 308 * 2048 / 4, n3 = 64 * 2048 / 4;
  int i = blockIdx.x * blockDim.x + threadIdx.x;
  const float* src; u16* dst; int j = i;
  if (i < n1) { src = hs; dst = hsb; }
  else if (i < n1 + n2) { src = ehs; dst = ehsb; j = i - n1; }
  else if (i < n1 + n2 + n3) { src = iph; dst = ipb; j = i - n1 - n2; }
  else return;
  float4 v = ((const float4*)src)[j];
  ushort4 o;
  o.x = f2b(v.x); o.y = f2b(v.y); o.z = f2b(v.z); o.w = f2b(v.w);
  ((ushort4*)dst)[j] = o;
}

// ---------------- weight transpose: W [K][N] fp32 -> WT [N][K] bf16 ----------------
__device__ __forceinline__ void transpose_tile(const float* __restrict__ W,
                                               u16* __restrict__ WT, int K, int N) {
  __shared__ float tile[32][33];
  int n0 = blockIdx.x * 32, k0 = blockIdx.y * 32;
  int tx = threadIdx.x & 31, ty = threadIdx.x >> 5;
#pragma unroll
  for (int i = 0; i < 32; i += 8)
    tile[ty + i][tx] = W[(size_t)(k0 + ty + i) * N + n0 + tx];
  __syncthreads();
#pragma unroll
  for (int i = 0; i < 32; i += 8)
    WT[(size_t)(n0 + ty + i) * K + k0 + tx] = f2b(tile[tx][ty + i]);
}

__global__ void k_transpose4(const float* W0, const float* W1, const float* W2,
                             const float* W3, u16* T0, u16* T1, u16* T2, u16* T3,
                             int K, int N) {
  int z = blockIdx.z;
  const float* W = (z == 0) ? W0 : (z == 1) ? W1 : (z == 2) ? W2 : W3;
  u16* T = (z == 0) ? T0 : (z == 1) ? T1 : (z == 2) ? T2 : T3;
  transpose_tile(W, T, K, N);
}
__global__ void k_transpose2(const float* W0, const float* W1, u16* T0, u16* T1,
                             int K, int N) {
  int z = blockIdx.z;
  transpose_tile(z ? W1 : W0, z ? T1 : T0, K, N);
}

// ---------------- small-GEMM core (128x128 tile), for K/V projections ----------------
__device__ __forceinline__ void gemm_core0(
    const u16* __restrict__ A, const u16* __restrict__ BT,
    int M, int N, int K, u16* __restrict__ outb, int m0, int n0) {
  const int tid = threadIdx.x;
  const int l = tid & 63;
  const int w = tid >> 6;
  const int wr = w >> 1, wc = w & 1;
  __shared__ u16 As[128 * 32];
  __shared__ u16 Bs[128 * 32];
  f32x4 acc[4][4] = {};

  const int o0 = tid * 16;
  const int o1 = o0 + 4096;
  const int ra0 = o0 >> 6, ca0 = (o0 & 63) >> 1;
  const int ra1 = o1 >> 6, ca1 = (o1 & 63) >> 1;
  int ga0 = m0 + ra0; if (ga0 >= M) ga0 = M - 1;
  int ga1 = m0 + ra1; if (ga1 >= M) ga1 = M - 1;
  const u16* Ar0 = A + (size_t)ga0 * K + ca0;
  const u16* Ar1 = A + (size_t)ga1 * K + ca1;
  const u16* Br0 = BT + (size_t)(n0 + ra0) * K + ca0;
  const u16* Br1 = BT + (size_t)(n0 + ra1) * K + ca1;

  for (int k0 = 0; k0 < K; k0 += 32) {
    gld16(Ar0 + k0, &As[o0 >> 1]);
    gld16(Ar1 + k0, &As[o1 >> 1]);
    gld16(Br0 + k0, &Bs[o0 >> 1]);
    gld16(Br1 + k0, &Bs[o1 >> 1]);
    __syncthreads();
    s16x8 af[4], bfr[4];
#pragma unroll
    for (int mi = 0; mi < 4; ++mi)
      af[mi] = *(const s16x8*)&As[(wr * 64 + mi * 16 + (l & 15)) * 32 + (l >> 4) * 8];
#pragma unroll
    for (int ni = 0; ni < 4; ++ni)
      bfr[ni] = *(const s16x8*)&Bs[(wc * 64 + ni * 16 + (l & 15)) * 32 + (l >> 4) * 8];
#pragma unroll
    for (int mi = 0; mi < 4; ++mi)
#pragma unroll
      for (int ni = 0; ni < 4; ++ni)
        acc[mi][ni] = mfma_bf16(af[mi], bfr[ni], acc[mi][ni]);
    __syncthreads();
  }

#pragma unroll
  for (int mi = 0; mi < 4; ++mi) {
    const int mbase = m0 + wr * 64 + mi * 16 + (l >> 4) * 4;
#pragma unroll
    for (int ni = 0; ni < 4; ++ni) {
      const int ncol = n0 + wc * 64 + ni * 16 + (l & 15);
#pragma unroll
      for (int r = 0; r < 4; ++r) {
        int m = mbase + r;
        if (m < M) outb[(size_t)m * N + ncol] = f2b(acc[mi][ni][r]);
      }
    }
  }
}

// the four K/V projections in one launch (z selects)
__global__ __launch_bounds__(256) void k_gemm_small4(
    const u16* __restrict__ ehsb, const u16* __restrict__ ipb,
    const u16* __restrict__ WkT, const u16* __restrict__ WvT,
    const u16* __restrict__ WkipT, const u16* __restrict__ WvipT,
    u16* kbuf, u16* vbuf, u16* kipb, u16* vipb) {
  const int z = blockIdx.z;
  const int M = (z < 2) ? 308 : 64;
  const int m0 = blockIdx.y * 128;
  if (m0 >= M) return;
  const u16* A = (z < 2) ? ehsb : ipb;
  const u16* BT = (z == 0) ? WkT : (z == 1) ? WvT : (z == 2) ? WkipT : WvipT;
  u16* out = (z == 0) ? kbuf : (z == 1) ? vbuf : (z == 2) ? kipb : vipb;
  gemm_core0(A, BT, M, 1280, 2048, out, m0, blockIdx.x * 128);
}

// ---------------- big GEMM: 256x320 tile, BK=32, RING-4 deep pipeline ----------------
// C[M,N] = A[M,K](bf16) * BT[N,K]^T.  M=16384, N=1280 (=4x320), K%32==0, KT=K/32.
// grid = exactly 256 blocks (1/CU).  8 waves 2(m)x4(n); wave tile 128x80.
// LDS 144KB = 4 ring slots x { A 256x32 (16KB) + B 320x32 (20KB) }.
// Tile j computes from slot j&3 while tile j+3 stages into slot (j+3)&3:
// issue-to-wait distance = 2 full tiles (~3000 cy) >> HBM latency (~900 cy).
// Per-wave loads/tile: A=2, B=3 (waves 0-3) or 2 (waves 4-7).
// End-of-tile wait leaves 2 staged tiles in flight: vmcnt(10)/(8); tail 5/4 then 0.
// Swizzle: rows are 64B = 4x16B slots; slot le stored at le^((row>>1)&3);
// global source col pre-permuted (both-sides-or-neither, rule #21).
template <int EPI>
__global__ __launch_bounds__(512, 1) void k_gemm256(
    const u16* __restrict__ A, const u16* __restrict__ BT,
    int N, int K, float alpha,
    u16* __restrict__ outb, float* __restrict__ outf,
    const float* __restrict__ bias, const u16* __restrict__ ipadd,
    int nbx) {
  __shared__ u16 lds[73728];  // A slots: [0,32768) u16, B slots: [32768,73728)
  const int tid = threadIdx.x, l = tid & 63, w = tid >> 6;
  const int lr = l & 15, lg = l >> 4;
  const int wr = w >> 2, wc = w & 3;
  const bool wlo = (w < 4);  // waves 0-3 carry the 3rd B staging chunk

  // bijective chunked XCD swizzle (T1); nwg=256 -> q=32, r=0
  const int nwg = gridDim.x;
  const int q = nwg >> 3, r = nwg & 7;
  const int xcd = blockIdx.x & 7, lid = blockIdx.x >> 3;
  const int wg = (xcd < r) ? (xcd * (q + 1) + lid)
                           : (r * (q + 1) + (xcd - r) * q + lid);
  const int bm0 = (wg / nbx) * 256, bn0 = (wg % nbx) * 320;

  // staging: chunk c -> row c>>2, dest slot c&3, source slot (c&3)^((row>>1)&3)
  const int srow = tid >> 2;
  const int sslot = ((tid & 3) ^ ((srow >> 1) & 3)) * 8;
  const size_t aO0 = (size_t)(bm0 + srow) * K + sslot;      // A rows 0-127
  const size_t aO1 = aO0 + (size_t)128 * K;                 // A rows 128-255
  const size_t bO0 = (size_t)(bn0 + srow) * K + sslot;      // B rows 0-127
  const size_t bO1 = bO0 + (size_t)128 * K;                 // B rows 128-255
  const size_t bO2 = bO0 + (size_t)256 * K;                 // B rows 256-319 (tid<256)
  const int d0 = tid * 8, d1 = (tid + 512) * 8, d2 = (tid + 1024) * 8;

  const int KT = K >> 5;
  f32x4 acc[8][5] = {};
  s16x8 bfv[5], afv[4];

  // frag read bases (u16 idx): + mi*512 / ni*512, + slot*8192 (A) / slot*10240 (B)
  const int xsw = (lg ^ ((lr >> 1) & 3)) * 8;
  const int aRow = (wr * 128 + lr) * 32 + xsw;
  const int bRow = 32768 + (wc * 80 + lr) * 32 + xsw;

#define STAGE_A(slot, kt)                                              \
  {                                                                    \
    const int base_ = (slot) * 8192;                                   \
    const size_t go_ = (size_t)(kt) * 32;                              \
    gld16(A + aO0 + go_, &lds[base_ + d0]);                            \
    gld16(A + aO1 + go_, &lds[base_ + d1]);                            \
  }
#define STAGE_B(slot, kt)                                              \
  {                                                                    \
    const int base_ = 32768 + (slot) * 10240;                          \
    const size_t go_ = (size_t)(kt) * 32;                              \
    gld16(BT + bO0 + go_, &lds[base_ + d0]);                           \
    gld16(BT + bO1 + go_, &lds[base_ + d1]);                           \
    if (wlo) gld16(BT + bO2 + go_, &lds[base_ + d2]);                  \
  }
#define WAIT_DEEP()                                                    \
  {                                                                    \
    if (wlo) asm volatile("s_waitcnt vmcnt(10)" ::: "memory");         \
    else     asm volatile("s_waitcnt vmcnt(8)" ::: "memory");          \
  }
#define WAIT_MID()                                                     \
  {                                                                    \
    if (wlo) asm volatile("s_waitcnt vmcnt(5)" ::: "memory");          \
    else     asm volatile("s_waitcnt vmcnt(4)" ::: "memory");          \
  }
#define WAITVM0() asm volatile("s_waitcnt vmcnt(0)" ::: "memory")

  // prologue: stage tiles 0,1,2 into slots 0,1,2
  STAGE_A(0, 0); STAGE_B(0, 0);
  STAGE_A(1, 1); STAGE_B(1, 1);
  STAGE_A(2, 2); STAGE_B(2, 2);
  WAIT_DEEP();  // tile 0 landed; tiles 1,2 in flight
  BAR();

  for (int j = 0; j < KT; ++j) {
    const int slot = j & 3;
    const int ab = slot * 8192;
    const int bb = slot * 10240;
    const bool pf = (j + 3 < KT);
    const int s3 = (j + 3) & 3;
    // ---- ph0: mi 0-3 ----
#pragma unroll
    for (int ni = 0; ni < 5; ++ni)
      bfv[ni] = *(const s16x8*)&lds[bb + bRow + ni * 512];
#pragma unroll
    for (int mi = 0; mi < 4; ++mi)
      afv[mi] = *(const s16x8*)&lds[ab + aRow + mi * 512];
    if (pf) STAGE_A(s3, j + 3);
    __builtin_amdgcn_s_setprio(1);
#pragma unroll
    for (int mi = 0; mi < 4; ++mi)
#pragma unroll
      for (int ni = 0; ni < 5; ++ni)
        acc[mi][ni] = mfma_bf16(afv[mi], bfv[ni], acc[mi][ni]);
    __builtin_amdgcn_s_setprio(0);
    BAR();
    // ---- ph1: mi 4-7 ----
#pragma unroll
    for (int mi = 0; mi < 4; ++mi)
      afv[mi] = *(const s16x8*)&lds[ab + aRow + (mi + 4) * 512];
    if (pf) STAGE_B(s3, j + 3);
    __builtin_amdgcn_s_setprio(1);
#pragma unroll
    for (int mi = 0; mi < 4; ++mi)
#pragma unroll
      for (int ni = 0; ni < 5; ++ni)
        acc[mi + 4][ni] = mfma_bf16(afv[mi], bfv[ni], acc[mi + 4][ni]);
    __builtin_amdgcn_s_setprio(0);
    // drain exactly the stage of tile j+1 (leaves deeper prefetch in flight)
    if (pf) { WAIT_DEEP(); }
    else if (j == KT - 3) { WAIT_MID(); }
    else { WAITVM0(); }
    BAR();
  }

  WAITVM0();
  __syncthreads();

  if constexpr (EPI == 0) {
    // repack through LDS in two 128-row halves -> full-line bf16 stores
#pragma unroll
    for (int half = 0; half < 2; ++half) {
      if (half) __syncthreads();
      if (wr == half) {
#pragma unroll
        for (int mi = 0; mi < 8; ++mi) {
          const int row = mi * 16 + lg * 4;
#pragma unroll
          for (int ni = 0; ni < 5; ++ni) {
            const int col = wc * 80 + ni * 16 + lr;
#pragma unroll
            for (int rr = 0; rr < 4; ++rr)
              lds[(row + rr) * 320 + col] = f2b(acc[mi][ni][rr] * alpha);
          }
        }
      }
      __syncthreads();
      // full-line stores: 8 lanes cover 128B contiguous of ONE row
      const int rbase = tid >> 3;  // 0..63
      const int cseg = tid & 7;    // 0..7
#pragma unroll
      for (int rr2 = 0; rr2 < 2; ++rr2)
#pragma unroll
        for (int jj = 0; jj < 5; ++jj) {
          const int row = rr2 * 64 + rbase;
          const int ch = cseg + jj * 8;  // 0..39
          *(int4*)(outb + (size_t)(bm0 + half * 128 + row) * N + bn0 + ch * 8) =
              *(const int4*)&lds[row * 320 + ch * 8];
        }
    }
  } else {
#pragma unroll
    for (int mi = 0; mi < 8; ++mi) {
      const int mrow = bm0 + wr * 128 + mi * 16 + lg * 4;
#pragma unroll
      for (int ni = 0; ni < 5; ++ni) {
        const int ncol = bn0 + wc * 80 + ni * 16 + lr;
#pragma unroll
        for (int rr = 0; rr < 4; ++rr) {
          const size_t idx = (size_t)(mrow + rr) * N + ncol;
          outf[idx] = acc[mi][ni][rr] + bias[ncol] + b2f(ipadd[idx]);
        }
      }
    }
  }
#undef STAGE_A
#undef STAGE_B
#undef WAIT_DEEP
#undef WAIT_MID
#undef WAITVM0
}

// ---------------- fused attention (main + IP stream) ----------------
// grid (32, 20, 4), 512 threads = 8 waves, 128 q-rows/block, 16 rows/wave.
// KV arena rows: 0..76 K, 77..79 zero, 80..95 Kip, 96..172 V, 173..175 zero,
// 176..191 Vip. Segment-XOR swizzle: 16B segment s of row stored at s^((row>>3)&3).
__global__ __launch_bounds__(512, 4) void k_attn(
    const u16* __restrict__ Q,    // [16384][1280], pre-scaled by 1/8
    const u16* __restrict__ Kb,   // [308][1280]
    const u16* __restrict__ Vb,
    const u16* __restrict__ Kip,  // [64][1280]
    const u16* __restrict__ Vip,
    const float* __restrict__ mask,  // [4096][77]
    u16* __restrict__ Oattn,      // [16384][1280] bf16
    u16* __restrict__ Oip) {
  const int qt = blockIdx.x, h = blockIdx.y, b = blockIdx.z;
  const int tid = threadIdx.x, l = tid & 63, w = tid >> 6;
  const int lr = l & 15, lg = l >> 4;
  const int r0 = w * 16;
  const int m0 = b * 4096 + qt * 128;

  __shared__ u16 KV[192][72];
  __shared__ u16 Ps[128][104];
  __shared__ u16 P2s[128][40];

  const u16* qrow = Q + (size_t)(m0 + r0 + lr) * 1280 + h * 64;
  s16x8 aq0 = *(const s16x8*)(qrow + lg * 8);
  s16x8 aq1 = *(const s16x8*)(qrow + 32 + lg * 8);

  for (int s = tid; s < 192 * 8; s += 512) {
    const int row = s >> 3, seg = s & 7;
    int4 v = {0, 0, 0, 0};
    const u16* src = nullptr;
    if (row < 77)       src = Kb  + (size_t)(b * 77 + row) * 1280 + h * 64 + seg * 8;
    else if (row < 80)  src = nullptr;
    else if (row < 96)  src = Kip + (size_t)(b * 16 + row - 80) * 1280 + h * 64 + seg * 8;
    else if (row < 173) src = Vb  + (size_t)(b * 77 + row - 96) * 1280 + h * 64 + seg * 8;
    else if (row < 176) src = nullptr;
    else                src = Vip + (size_t)(b * 16 + row - 176) * 1280 + h * 64 + seg * 8;
    if (src) v = *(const int4*)src;
    *(int4*)&KV[row][(seg ^ ((row >> 3) & 3)) * 8] = v;
  }
  __syncthreads();

  f32x4 sc[5];
  f32x4 sip = {};
#pragma unroll
  for (int t5 = 0; t5 < 6; ++t5) {
    const int trow = t5 * 16 + lr;
    const int qz = (trow >> 3) & 3;
    s16x8 b0 = *(const s16x8*)&KV[trow][(lg ^ qz) * 8];
    s16x8 b1 = *(const s16x8*)&KV[trow][((lg + 4) ^ qz) * 8];
    f32x4 c = {};
    c = mfma_bf16(aq0, b0, c);
    c = mfma_bf16(aq1, b1, c);
    if (t5 < 5) sc[t5] = c; else sip = c;
  }

#pragma unroll
  for (int r = 0; r < 4; ++r) {
    float mx = fmaxf(fmaxf(fmaxf(sc[0][r], sc[1][r]), fmaxf(sc[2][r], sc[3][r])), sc[4][r]);
    mx = fmaxf(mx, __shfl_xor(mx, 1));
    mx = fmaxf(mx, __shfl_xor(mx, 2));
    mx = fmaxf(mx, __shfl_xor(mx, 4));
    mx = fmaxf(mx, __shfl_xor(mx, 8));
    float p[5], sm = 0.f;
#pragma unroll
    for (int t5 = 0; t5 < 5; ++t5) {
      bool valid = (t5 < 4) | (lr < 13);
      p[t5] = valid ? __expf(sc[t5][r] - mx) : 0.f;
      sm += p[t5];
    }
    sm += __shfl_xor(sm, 1);
    sm += __shfl_xor(sm, 2);
    sm += __shfl_xor(sm, 4);
    sm += __shfl_xor(sm, 8);
    const float inv = 1.0f / sm;
    const int row = r0 + lg * 4 + r;
    const int qg = qt * 128 + row;
#pragma unroll
    for (int t5 = 0; t5 < 5; ++t5) {
      int t = t5 * 16 + lr;
      float pf = 0.f;
      if (t < 77) pf = p[t5] * inv * mask[qg * 77 + t];
      Ps[row][t] = f2b(pf);
    }
    Ps[row][80 + lr] = 0;

    float m2 = sip[r];
    m2 = fmaxf(m2, __shfl_xor(m2, 1));
    m2 = fmaxf(m2, __shfl_xor(m2, 2));
    m2 = fmaxf(m2, __shfl_xor(m2, 4));
    m2 = fmaxf(m2, __shfl_xor(m2, 8));
    float pi = __expf(sip[r] - m2);
    float s2 = pi;
    s2 += __shfl_xor(s2, 1);
    s2 += __shfl_xor(s2, 2);
    s2 += __shfl_xor(s2, 4);
    s2 += __shfl_xor(s2, 8);
    P2s[row][lr] = 0;
    P2s[row][16 + lr] = f2b(pi / s2);
  }

  s16x8 ap[3];
#pragma unroll
  for (int ks = 0; ks < 3; ++ks)
    ap[ks] = *(const s16x8*)&Ps[r0 + lr][ks * 32 + lg * 8];
  s16x8 aip = *(const s16x8*)&P2s[r0 + lr][lg * 8];

  f32x4 om[4], oi[4];
#pragma unroll
  for (int nt = 0; nt < 4; ++nt) {
    const int dcol = (nt * 16 + lr) ^ (lg << 3);
    f32x4 o = {};
#pragma unroll
    for (int ks = 0; ks < 3; ++ks) {
      s16x8 bv;
#pragma unroll
      for (int j = 0; j < 8; ++j)
        bv[j] = (short)KV[96 + ks * 32 + lg * 8 + j][dcol];
      o = mfma_bf16(ap[ks], bv, o);
    }
    s16x8 bip;
#pragma unroll
    for (int j = 0; j < 8; ++j)
      bip[j] = (short)KV[160 + lg * 8 + j][dcol];
    f32x4 o2 = {};
    o2 = mfma_bf16(aip, bip, o2);
    om[nt] = o;
    oi[nt] = o2;
  }

  __syncthreads();

  u16 (*Om)[72] = (u16(*)[72]) & KV[0][0];
  u16 (*Oi)[72] = (u16(*)[72]) & Ps[0][0];
#pragma unroll
  for (int nt = 0; nt < 4; ++nt)
#pragma unroll
    for (int r = 0; r < 4; ++r) {
      const int row = r0 + lg * 4 + r;
      const int d = nt * 16 + lr;
      Om[row][d] = f2b(om[nt][r]);
      Oi[row][d] = f2b(oi[nt][r]);
    }
  __syncthreads();

  for (int s = tid; s < 128 * 8; s += 512) {
    const int row = s >> 3, seg = s & 7;
    const size_t g = (size_t)(m0 + row) * 1280 + h * 64 + seg * 8;
    *(int4*)(Oattn + g) = *(const int4*)&Om[row][seg * 8];
    *(int4*)(Oip + g) = *(const int4*)&Oi[row][seg * 8];
  }
}

// ---------------- launch ----------------
extern "C" void kernel_launch(void* const* d_in, const int* in_sizes, int n_in,
                              void* d_out, int out_size, void* d_ws, size_t ws_size,
                              hipStream_t stream) {
  (void)in_sizes; (void)n_in; (void)out_size; (void)ws_size;
  const float* hs   = (const float*)d_in[0];
  const float* ehs  = (const float*)d_in[1];
  const float* iph  = (const float*)d_in[2];
  const float* mask = (const float*)d_in[3];
  const float* Wq   = (const float*)d_in[4];
  const float* Wk   = (const float*)d_in[5];
  const float* Wv   = (const float*)d_in[6];
  const float* Wo   = (const float*)d_in[7];
  const float* bo   = (const float*)d_in[8];
  const float* Wkip = (const float*)d_in[9];
  const float* Wvip = (const float*)d_in[10];
  float* out = (float*)d_out;

  char* ws = (char*)d_ws;
  size_t off = 0;
  auto alloc = [&](size_t bytes) {
    char* p = ws + off;
    off += (bytes + 255) & ~(size_t)255;
    return p;
  };
  u16* hsb   = (u16*)alloc(16384ull * 1280 * 2);  // reused as attn_out
  u16* qbuf  = (u16*)alloc(16384ull * 1280 * 2);
  u16* ipout = (u16*)alloc(16384ull * 1280 * 2);
  u16* WqT   = (u16*)alloc(1280ull * 1280 * 2);
  u16* WoT   = (u16*)alloc(1280ull * 1280 * 2);
  u16* WkT   = (u16*)alloc(1280ull * 2048 * 2);
  u16* WvT   = (u16*)alloc(1280ull * 2048 * 2);
  u16* WkipT = (u16*)alloc(1280ull * 2048 * 2);
  u16* WvipT = (u16*)alloc(1280ull * 2048 * 2);
  u16* ehsb  = (u16*)alloc(308ull * 2048 * 2);
  u16* ipb   = (u16*)alloc(64ull * 2048 * 2);
  u16* kbuf  = (u16*)alloc(308ull * 1280 * 2);
  u16* vbuf  = (u16*)alloc(308ull * 1280 * 2);
  u16* kipb  = (u16*)alloc(64ull * 1280 * 2);
  u16* vipb  = (u16*)alloc(64ull * 1280 * 2);

  const int ntot4 = (16384 * 1280 + 308 * 2048 + 64 * 2048) / 4;
  k_convert_all<<<(ntot4 + 255) / 256, 256, 0, stream>>>(hs, ehs, iph, hsb, ehsb, ipb);
  k_transpose4<<<dim3(40, 64, 4), 256, 0, stream>>>(Wk, Wv, Wkip, Wvip,
                                                    WkT, WvT, WkipT, WvipT, 2048, 1280);
  k_transpose2<<<dim3(40, 40, 2), 256, 0, stream>>>(Wq, Wo, WqT, WoT, 1280, 1280);

  // Q projection (scale 1/8 baked in): 64 x 4 = 256 blocks, 1/CU
  k_gemm256<0><<<256, 512, 0, stream>>>(hsb, WqT, 1280, 1280, 0.125f,
                                        qbuf, nullptr, nullptr, nullptr, 4);
  // K/V/Kip/Vip projections in one launch
  k_gemm_small4<<<dim3(10, 3, 4), 256, 0, stream>>>(ehsb, ipb, WkT, WvT, WkipT, WvipT,
                                                    kbuf, vbuf, kipb, vipb);

  // fused attention (main + IP). attn_out overwrites hsb.
  k_attn<<<dim3(32, 20, 4), 512, 0, stream>>>(qbuf, kbuf, vbuf, kipb, vipb, mask,
                                              hsb, ipout);

  // out = attn_out @ Wo + bo + ip_out
  k_gemm256<1><<<256, 512, 0, stream>>>(hsb, WoT, 1280, 1280, 1.f,
                                        nullptr, out, bo, ipout, 4);
}

// Round 8
// 265.388 us; speedup vs baseline: 1.0038x; 1.0038x over previous
//
#include <hip/hip_runtime.h>

typedef __attribute__((ext_vector_type(4))) float f32x4;
typedef __attribute__((ext_vector_type(8))) short s16x8;
typedef __attribute__((ext_vector_type(8))) __bf16 bf16x8;
typedef unsigned short u16;

__device__ __forceinline__ u16 f2b(float f) {
  union { float f; unsigned u; } x; x.f = f;
  unsigned r = x.u + 0x7fffu + ((x.u >> 16) & 1u);
  return (u16)(r >> 16);
}
__device__ __forceinline__ float b2f(u16 u) {
  union { unsigned u; float f; } x; x.u = ((unsigned)u) << 16;
  return x.f;
}
__device__ __forceinline__ void gld16(const void* g, void* l) {
  __builtin_amdgcn_global_load_lds(
      (const __attribute__((address_space(1))) unsigned int*)g,
      (__attribute__((address_space(3))) unsigned int*)l, 16, 0, 0);
}
__device__ __forceinline__ f32x4 mfma_bf16(s16x8 a, s16x8 b, f32x4 c) {
  return __builtin_amdgcn_mfma_f32_16x16x32_bf16(
      __builtin_bit_cast(bf16x8, a), __builtin_bit_cast(bf16x8, b), c, 0, 0, 0);
}

#define BAR() asm volatile("s_barrier" ::: "memory")

// ---------------- fused fp32->bf16 conversion (all three activations) ----------------
__global__ void k_convert_all(const float* __restrict__ hs, const float* __restrict__ ehs,
                              const float* __restrict__ iph,
                              u16* __restrict__ hsb, u16* __restrict__ ehsb,
                              u16* __restrict__ ipb) {
  const int n1 = 16384 * 1280 / 4, n2 = 308 * 2048 / 4, n3 = 64 * 2048 / 4;
  int i = blockIdx.x * blockDim.x + threadIdx.x;
  const float* src; u16* dst; int j = i;
  if (i < n1) { src = hs; dst = hsb; }
  else if (i < n1 + n2) { src = ehs; dst = ehsb; j = i - n1; }
  else if (i < n1 + n2 + n3) { src = iph; dst = ipb; j = i - n1 - n2; }
  else return;
  float4 v = ((const float4*)src)[j];
  ushort4 o;
  o.x = f2b(v.x); o.y = f2b(v.y); o.z = f2b(v.z); o.w = f2b(v.w);
  ((ushort4*)dst)[j] = o;
}

// ---------------- weight transpose: W [K][N] fp32 -> WT [N][K] bf16 ----------------
__device__ __forceinline__ void transpose_tile(const float* __restrict__ W,
                                               u16* __restrict__ WT, int K, int N) {
  __shared__ float tile[32][33];
  int n0 = blockIdx.x * 32, k0 = blockIdx.y * 32;
  int tx = threadIdx.x & 31, ty = threadIdx.x >> 5;
#pragma unroll
  for (int i = 0; i < 32; i += 8)
    tile[ty + i][tx] = W[(size_t)(k0 + ty + i) * N + n0 + tx];
  __syncthreads();
#pragma unroll
  for (int i = 0; i < 32; i += 8)
    WT[(size_t)(n0 + ty + i) * K + k0 + tx] = f2b(tile[tx][ty + i]);
}

__global__ void k_transpose4(const float* W0, const float* W1, const float* W2,
                             const float* W3, u16* T0, u16* T1, u16* T2, u16* T3,
                             int K, int N) {
  int z = blockIdx.z;
  const float* W = (z == 0) ? W0 : (z == 1) ? W1 : (z == 2) ? W2 : W3;
  u16* T = (z == 0) ? T0 : (z == 1) ? T1 : (z == 2) ? T2 : T3;
  transpose_tile(W, T, K, N);
}
__global__ void k_transpose2(const float* W0, const float* W1, u16* T0, u16* T1,
                             int K, int N) {
  int z = blockIdx.z;
  transpose_tile(z ? W1 : W0, z ? T1 : T0, K, N);
}

// ---------------- small-GEMM core (128x128 tile), for K/V projections ----------------
__device__ __forceinline__ void gemm_core0(
    const u16* __restrict__ A, const u16* __restrict__ BT,
    int M, int N, int K, u16* __restrict__ outb, int m0, int n0) {
  const int tid = threadIdx.x;
  const int l = tid & 63;
  const int w = tid >> 6;
  const int wr = w >> 1, wc = w & 1;
  __shared__ u16 As[128 * 32];
  __shared__ u16 Bs[128 * 32];
  f32x4 acc[4][4] = {};

  const int o0 = tid * 16;
  const int o1 = o0 + 4096;
  const int ra0 = o0 >> 6, ca0 = (o0 & 63) >> 1;
  const int ra1 = o1 >> 6, ca1 = (o1 & 63) >> 1;
  int ga0 = m0 + ra0; if (ga0 >= M) ga0 = M - 1;
  int ga1 = m0 + ra1; if (ga1 >= M) ga1 = M - 1;
  const u16* Ar0 = A + (size_t)ga0 * K + ca0;
  const u16* Ar1 = A + (size_t)ga1 * K + ca1;
  const u16* Br0 = BT + (size_t)(n0 + ra0) * K + ca0;
  const u16* Br1 = BT + (size_t)(n0 + ra1) * K + ca1;

  for (int k0 = 0; k0 < K; k0 += 32) {
    gld16(Ar0 + k0, &As[o0 >> 1]);
    gld16(Ar1 + k0, &As[o1 >> 1]);
    gld16(Br0 + k0, &Bs[o0 >> 1]);
    gld16(Br1 + k0, &Bs[o1 >> 1]);
    __syncthreads();
    s16x8 af[4], bfr[4];
#pragma unroll
    for (int mi = 0; mi < 4; ++mi)
      af[mi] = *(const s16x8*)&As[(wr * 64 + mi * 16 + (l & 15)) * 32 + (l >> 4) * 8];
#pragma unroll
    for (int ni = 0; ni < 4; ++ni)
      bfr[ni] = *(const s16x8*)&Bs[(wc * 64 + ni * 16 + (l & 15)) * 32 + (l >> 4) * 8];
#pragma unroll
    for (int mi = 0; mi < 4; ++mi)
#pragma unroll
      for (int ni = 0; ni < 4; ++ni)
        acc[mi][ni] = mfma_bf16(af[mi], bfr[ni], acc[mi][ni]);
    __syncthreads();
  }

#pragma unroll
  for (int mi = 0; mi < 4; ++mi) {
    const int mbase = m0 + wr * 64 + mi * 16 + (l >> 4) * 4;
#pragma unroll
    for (int ni = 0; ni < 4; ++ni) {
      const int ncol = n0 + wc * 64 + ni * 16 + (l & 15);
#pragma unroll
      for (int r = 0; r < 4; ++r) {
        int m = mbase + r;
        if (m < M) outb[(size_t)m * N + ncol] = f2b(acc[mi][ni][r]);
      }
    }
  }
}

// the four K/V projections in one launch (z selects)
__global__ __launch_bounds__(256) void k_gemm_small4(
    const u16* __restrict__ ehsb, const u16* __restrict__ ipb,
    const u16* __restrict__ WkT, const u16* __restrict__ WvT,
    const u16* __restrict__ WkipT, const u16* __restrict__ WvipT,
    u16* kbuf, u16* vbuf, u16* kipb, u16* vipb) {
  const int z = blockIdx.z;
  const int M = (z < 2) ? 308 : 64;
  const int m0 = blockIdx.y * 128;
  if (m0 >= M) return;
  const u16* A = (z < 2) ? ehsb : ipb;
  const u16* BT = (z == 0) ? WkT : (z == 1) ? WvT : (z == 2) ? WkipT : WvipT;
  u16* out = (z == 0) ? kbuf : (z == 1) ? vbuf : (z == 2) ? kipb : vipb;
  gemm_core0(A, BT, M, 1280, 2048, out, m0, blockIdx.x * 128);
}

// ---------------- big GEMM: 256x320 tile, BK=32, RING-4, ONE barrier per K-tile -----
// C[M,N] = A[M,K](bf16) * BT[N,K]^T.  M=16384, N=1280 (=4x320), K%32==0, KT=K/32.
// grid = exactly 256 blocks (1/CU).  8 waves 2(m)x4(n); wave tile 128x80.
// LDS 144KB = 4 ring slots x { A 256x32 (16KB) + B 320x32 (20KB) }.
// Tile j computes slot j&3 while staging tile j+3 into slot (j+3)&3.
// ONE s_barrier per tile: waves drift inside the tile region, so one wave's
// ds_reads overlap the other SIMD-wave's MFMA cluster (LDS pipe || MFMA pipe).
// Safety: earliest slot reuse is tile j+1 writing slot j&3, which is only
// reachable after ALL waves passed tile j's barrier (all slot-j reads done).
// Per-wave WAIT before the barrier drains exactly tile j+1's stage.
template <int EPI>
__global__ __launch_bounds__(512, 1) void k_gemm256(
    const u16* __restrict__ A, const u16* __restrict__ BT,
    int N, int K, float alpha,
    u16* __restrict__ outb, float* __restrict__ outf,
    const float* __restrict__ bias, const u16* __restrict__ ipadd,
    int nbx) {
  __shared__ u16 lds[73728];  // A slots: [0,32768) u16, B slots: [32768,73728)
  const int tid = threadIdx.x, l = tid & 63, w = tid >> 6;
  const int lr = l & 15, lg = l >> 4;
  const int wr = w >> 2, wc = w & 3;
  const bool wlo = (w < 4);  // waves 0-3 carry the 3rd B staging chunk

  // bijective chunked XCD swizzle (T1); nwg=256 -> q=32, r=0
  const int nwg = gridDim.x;
  const int q = nwg >> 3, r = nwg & 7;
  const int xcd = blockIdx.x & 7, lid = blockIdx.x >> 3;
  const int wg = (xcd < r) ? (xcd * (q + 1) + lid)
                           : (r * (q + 1) + (xcd - r) * q + lid);
  const int bm0 = (wg / nbx) * 256, bn0 = (wg % nbx) * 320;

  // staging: chunk c -> row c>>2, dest slot c&3, source slot (c&3)^((row>>1)&3)
  const int srow = tid >> 2;
  const int sslot = ((tid & 3) ^ ((srow >> 1) & 3)) * 8;
  const size_t aO0 = (size_t)(bm0 + srow) * K + sslot;      // A rows 0-127
  const size_t aO1 = aO0 + (size_t)128 * K;                 // A rows 128-255
  const size_t bO0 = (size_t)(bn0 + srow) * K + sslot;      // B rows 0-127
  const size_t bO1 = bO0 + (size_t)128 * K;                 // B rows 128-255
  const size_t bO2 = bO0 + (size_t)256 * K;                 // B rows 256-319 (tid<256)
  const int d0 = tid * 8, d1 = (tid + 512) * 8, d2 = (tid + 1024) * 8;

  const int KT = K >> 5;
  f32x4 acc[8][5] = {};
  s16x8 bfv[5], afv[4];

  // frag read bases (u16 idx): + mi*512 / ni*512, + slot*8192 (A) / slot*10240 (B)
  const int xsw = (lg ^ ((lr >> 1) & 3)) * 8;
  const int aRow = (wr * 128 + lr) * 32 + xsw;
  const int bRow = 32768 + (wc * 80 + lr) * 32 + xsw;

#define STAGE_A(slot, kt)                                              \
  {                                                                    \
    const int base_ = (slot) * 8192;                                   \
    const size_t go_ = (size_t)(kt) * 32;                              \
    gld16(A + aO0 + go_, &lds[base_ + d0]);                            \
    gld16(A + aO1 + go_, &lds[base_ + d1]);                            \
  }
#define STAGE_B(slot, kt)                                              \
  {                                                                    \
    const int base_ = 32768 + (slot) * 10240;                          \
    const size_t go_ = (size_t)(kt) * 32;                              \
    gld16(BT + bO0 + go_, &lds[base_ + d0]);                           \
    gld16(BT + bO1 + go_, &lds[base_ + d1]);                           \
    if (wlo) gld16(BT + bO2 + go_, &lds[base_ + d2]);                  \
  }
#define WAIT_DEEP()                                                    \
  {                                                                    \
    if (wlo) asm volatile("s_waitcnt vmcnt(10)" ::: "memory");         \
    else     asm volatile("s_waitcnt vmcnt(8)" ::: "memory");          \
  }
#define WAIT_MID()                                                     \
  {                                                                    \
    if (wlo) asm volatile("s_waitcnt vmcnt(5)" ::: "memory");          \
    else     asm volatile("s_waitcnt vmcnt(4)" ::: "memory");          \
  }
#define WAITVM0() asm volatile("s_waitcnt vmcnt(0)" ::: "memory")

  // prologue: stage tiles 0,1,2 into slots 0,1,2
  STAGE_A(0, 0); STAGE_B(0, 0);
  STAGE_A(1, 1); STAGE_B(1, 1);
  STAGE_A(2, 2); STAGE_B(2, 2);
  WAIT_DEEP();  // tile 0 landed; tiles 1,2 in flight
  BAR();

  for (int j = 0; j < KT; ++j) {
    const int slot = j & 3;
    const int ab = slot * 8192;
    const int bb = slot * 10240;
    const bool pf = (j + 3 < KT);
    const int s3 = (j + 3) & 3;
    // ---- merged tile body: reads + stage + 2 MFMA clusters, no mid barrier ----
#pragma unroll
    for (int ni = 0; ni < 5; ++ni)
      bfv[ni] = *(const s16x8*)&lds[bb + bRow + ni * 512];
#pragma unroll
    for (int mi = 0; mi < 4; ++mi)
      afv[mi] = *(const s16x8*)&lds[ab + aRow + mi * 512];
    if (pf) STAGE_A(s3, j + 3);
    __builtin_amdgcn_s_setprio(1);
#pragma unroll
    for (int mi = 0; mi < 4; ++mi)
#pragma unroll
      for (int ni = 0; ni < 5; ++ni)
        acc[mi][ni] = mfma_bf16(afv[mi], bfv[ni], acc[mi][ni]);
    __builtin_amdgcn_s_setprio(0);
#pragma unroll
    for (int mi = 0; mi < 4; ++mi)
      afv[mi] = *(const s16x8*)&lds[ab + aRow + (mi + 4) * 512];
    if (pf) STAGE_B(s3, j + 3);
    __builtin_amdgcn_s_setprio(1);
#pragma unroll
    for (int mi = 0; mi < 4; ++mi)
#pragma unroll
      for (int ni = 0; ni < 5; ++ni)
        acc[mi + 4][ni] = mfma_bf16(afv[mi], bfv[ni], acc[mi + 4][ni]);
    __builtin_amdgcn_s_setprio(0);
    // drain exactly the stage of tile j+1 (leaves deeper prefetch in flight)
    if (pf) { WAIT_DEEP(); }
    else if (j == KT - 3) { WAIT_MID(); }
    else { WAITVM0(); }
    BAR();
  }

  WAITVM0();
  __syncthreads();

  if constexpr (EPI == 0) {
    // repack through LDS in two 128-row halves -> full-line bf16 stores
#pragma unroll
    for (int half = 0; half < 2; ++half) {
      if (half) __syncthreads();
      if (wr == half) {
#pragma unroll
        for (int mi = 0; mi < 8; ++mi) {
          const int row = mi * 16 + lg * 4;
#pragma unroll
          for (int ni = 0; ni < 5; ++ni) {
            const int col = wc * 80 + ni * 16 + lr;
#pragma unroll
            for (int rr = 0; rr < 4; ++rr)
              lds[(row + rr) * 320 + col] = f2b(acc[mi][ni][rr] * alpha);
          }
        }
      }
      __syncthreads();
      // full-line stores: 8 lanes cover 128B contiguous of ONE row
      const int rbase = tid >> 3;  // 0..63
      const int cseg = tid & 7;    // 0..7
#pragma unroll
      for (int rr2 = 0; rr2 < 2; ++rr2)
#pragma unroll
        for (int jj = 0; jj < 5; ++jj) {
          const int row = rr2 * 64 + rbase;
          const int ch = cseg + jj * 8;  // 0..39
          *(int4*)(outb + (size_t)(bm0 + half * 128 + row) * N + bn0 + ch * 8) =
              *(const int4*)&lds[row * 320 + ch * 8];
        }
    }
  } else {
#pragma unroll
    for (int mi = 0; mi < 8; ++mi) {
      const int mrow = bm0 + wr * 128 + mi * 16 + lg * 4;
#pragma unroll
      for (int ni = 0; ni < 5; ++ni) {
        const int ncol = bn0 + wc * 80 + ni * 16 + lr;
#pragma unroll
        for (int rr = 0; rr < 4; ++rr) {
          const size_t idx = (size_t)(mrow + rr) * N + ncol;
          outf[idx] = acc[mi][ni][rr] + bias[ncol] + b2f(ipadd[idx]);
        }
      }
    }
  }
#undef STAGE_A
#undef STAGE_B
#undef WAIT_DEEP
#undef WAIT_MID
#undef WAITVM0
}

// ---------------- fused attention (main + IP stream) ----------------
// grid (32, 20, 4), 512 threads = 8 waves, 128 q-rows/block, 16 rows/wave.
// KV arena rows: 0..76 K, 77..79 zero, 80..95 Kip, 96..172 V, 173..175 zero,
// 176..191 Vip. Segment-XOR swizzle: 16B segment s of row stored at s^((row>>3)&3).
__global__ __launch_bounds__(512, 4) void k_attn(
    const u16* __restrict__ Q,    // [16384][1280], pre-scaled by 1/8
    const u16* __restrict__ Kb,   // [308][1280]
    const u16* __restrict__ Vb,
    const u16* __restrict__ Kip,  // [64][1280]
    const u16* __restrict__ Vip,
    const float* __restrict__ mask,  // [4096][77]
    u16* __restrict__ Oattn,      // [16384][1280] bf16
    u16* __restrict__ Oip) {
  const int qt = blockIdx.x, h = blockIdx.y, b = blockIdx.z;
  const int tid = threadIdx.x, l = tid & 63, w = tid >> 6;
  const int lr = l & 15, lg = l >> 4;
  const int r0 = w * 16;
  const int m0 = b * 4096 + qt * 128;

  __shared__ u16 KV[192][72];
  __shared__ u16 Ps[128][104];
  __shared__ u16 P2s[128][40];

  const u16* qrow = Q + (size_t)(m0 + r0 + lr) * 1280 + h * 64;
  s16x8 aq0 = *(const s16x8*)(qrow + lg * 8);
  s16x8 aq1 = *(const s16x8*)(qrow + 32 + lg * 8);

  for (int s = tid; s < 192 * 8; s += 512) {
    const int row = s >> 3, seg = s & 7;
    int4 v = {0, 0, 0, 0};
    const u16* src = nullptr;
    if (row < 77)       src = Kb  + (size_t)(b * 77 + row) * 1280 + h * 64 + seg * 8;
    else if (row < 80)  src = nullptr;
    else if (row < 96)  src = Kip + (size_t)(b * 16 + row - 80) * 1280 + h * 64 + seg * 8;
    else if (row < 173) src = Vb  + (size_t)(b * 77 + row - 96) * 1280 + h * 64 + seg * 8;
    else if (row < 176) src = nullptr;
    else                src = Vip + (size_t)(b * 16 + row - 176) * 1280 + h * 64 + seg * 8;
    if (src) v = *(const int4*)src;
    *(int4*)&KV[row][(seg ^ ((row >> 3) & 3)) * 8] = v;
  }
  __syncthreads();

  f32x4 sc[5];
  f32x4 sip = {};
#pragma unroll
  for (int t5 = 0; t5 < 6; ++t5) {
    const int trow = t5 * 16 + lr;
    const int qz = (trow >> 3) & 3;
    s16x8 b0 = *(const s16x8*)&KV[trow][(lg ^ qz) * 8];
    s16x8 b1 = *(const s16x8*)&KV[trow][((lg + 4) ^ qz) * 8];
    f32x4 c = {};
    c = mfma_bf16(aq0, b0, c);
    c = mfma_bf16(aq1, b1, c);
    if (t5 < 5) sc[t5] = c; else sip = c;
  }

#pragma unroll
  for (int r = 0; r < 4; ++r) {
    float mx = fmaxf(fmaxf(fmaxf(sc[0][r], sc[1][r]), fmaxf(sc[2][r], sc[3][r])), sc[4][r]);
    mx = fmaxf(mx, __shfl_xor(mx, 1));
    mx = fmaxf(mx, __shfl_xor(mx, 2));
    mx = fmaxf(mx, __shfl_xor(mx, 4));
    mx = fmaxf(mx, __shfl_xor(mx, 8));
    float p[5], sm = 0.f;
#pragma unroll
    for (int t5 = 0; t5 < 5; ++t5) {
      bool valid = (t5 < 4) | (lr < 13);
      p[t5] = valid ? __expf(sc[t5][r] - mx) : 0.f;
      sm += p[t5];
    }
    sm += __shfl_xor(sm, 1);
    sm += __shfl_xor(sm, 2);
    sm += __shfl_xor(sm, 4);
    sm += __shfl_xor(sm, 8);
    const float inv = 1.0f / sm;
    const int row = r0 + lg * 4 + r;
    const int qg = qt * 128 + row;
#pragma unroll
    for (int t5 = 0; t5 < 5; ++t5) {
      int t = t5 * 16 + lr;
      float pf = 0.f;
      if (t < 77) pf = p[t5] * inv * mask[qg * 77 + t];
      Ps[row][t] = f2b(pf);
    }
    Ps[row][80 + lr] = 0;

    float m2 = sip[r];
    m2 = fmaxf(m2, __shfl_xor(m2, 1));
    m2 = fmaxf(m2, __shfl_xor(m2, 2));
    m2 = fmaxf(m2, __shfl_xor(m2, 4));
    m2 = fmaxf(m2, __shfl_xor(m2, 8));
    float pi = __expf(sip[r] - m2);
    float s2 = pi;
    s2 += __shfl_xor(s2, 1);
    s2 += __shfl_xor(s2, 2);
    s2 += __shfl_xor(s2, 4);
    s2 += __shfl_xor(s2, 8);
    P2s[row][lr] = 0;
    P2s[row][16 + lr] = f2b(pi / s2);
  }

  s16x8 ap[3];
#pragma unroll
  for (int ks = 0; ks < 3; ++ks)
    ap[ks] = *(const s16x8*)&Ps[r0 + lr][ks * 32 + lg * 8];
  s16x8 aip = *(const s16x8*)&P2s[r0 + lr][lg * 8];

  f32x4 om[4], oi[4];
#pragma unroll
  for (int nt = 0; nt < 4; ++nt) {
    const int dcol = (nt * 16 + lr) ^ (lg << 3);
    f32x4 o = {};
#pragma unroll
    for (int ks = 0; ks < 3; ++ks) {
      s16x8 bv;
#pragma unroll
      for (int j = 0; j < 8; ++j)
        bv[j] = (short)KV[96 + ks * 32 + lg * 8 + j][dcol];
      o = mfma_bf16(ap[ks], bv, o);
    }
    s16x8 bip;
#pragma unroll
    for (int j = 0; j < 8; ++j)
      bip[j] = (short)KV[160 + lg * 8 + j][dcol];
    f32x4 o2 = {};
    o2 = mfma_bf16(aip, bip, o2);
    om[nt] = o;
    oi[nt] = o2;
  }

  __syncthreads();

  u16 (*Om)[72] = (u16(*)[72]) & KV[0][0];
  u16 (*Oi)[72] = (u16(*)[72]) & Ps[0][0];
#pragma unroll
  for (int nt = 0; nt < 4; ++nt)
#pragma unroll
    for (int r = 0; r < 4; ++r) {
      const int row = r0 + lg * 4 + r;
      const int d = nt * 16 + lr;
      Om[row][d] = f2b(om[nt][r]);
      Oi[row][d] = f2b(oi[nt][r]);
    }
  __syncthreads();

  for (int s = tid; s < 128 * 8; s += 512) {
    const int row = s >> 3, seg = s & 7;
    const size_t g = (size_t)(m0 + row) * 1280 + h * 64 + seg * 8;
    *(int4*)(Oattn + g) = *(const int4*)&Om[row][seg * 8];
    *(int4*)(Oip + g) = *(const int4*)&Oi[row][seg * 8];
  }
}

// ---------------- launch ----------------
extern "C" void kernel_launch(void* const* d_in, const int* in_sizes, int n_in,
                              void* d_out, int out_size, void* d_ws, size_t ws_size,
                              hipStream_t stream) {
  (void)in_sizes; (void)n_in; (void)out_size; (void)ws_size;
  const float* hs   = (const float*)d_in[0];
  const float* ehs  = (const float*)d_in[1];
  const float* iph  = (const float*)d_in[2];
  const float* mask = (const float*)d_in[3];
  const float* Wq   = (const float*)d_in[4];
  const float* Wk   = (const float*)d_in[5];
  const float* Wv   = (const float*)d_in[6];
  const float* Wo   = (const float*)d_in[7];
  const float* bo   = (const float*)d_in[8];
  const float* Wkip = (const float*)d_in[9];
  const float* Wvip = (const float*)d_in[10];
  float* out = (float*)d_out;

  char* ws = (char*)d_ws;
  size_t off = 0;
  auto alloc = [&](size_t bytes) {
    char* p = ws + off;
    off += (bytes + 255) & ~(size_t)255;
    return p;
  };
  u16* hsb   = (u16*)alloc(16384ull * 1280 * 2);  // reused as attn_out
  u16* qbuf  = (u16*)alloc(16384ull * 1280 * 2);
  u16* ipout = (u16*)alloc(16384ull * 1280 * 2);
  u16* WqT   = (u16*)alloc(1280ull * 1280 * 2);
  u16* WoT   = (u16*)alloc(1280ull * 1280 * 2);
  u16* WkT   = (u16*)alloc(1280ull * 2048 * 2);
  u16* WvT   = (u16*)alloc(1280ull * 2048 * 2);
  u16* WkipT = (u16*)alloc(1280ull * 2048 * 2);
  u16* WvipT = (u16*)alloc(1280ull * 2048 * 2);
  u16* ehsb  = (u16*)alloc(308ull * 2048 * 2);
  u16* ipb   = (u16*)alloc(64ull * 2048 * 2);
  u16* kbuf  = (u16*)alloc(308ull * 1280 * 2);
  u16* vbuf  = (u16*)alloc(308ull * 1280 * 2);
  u16* kipb  = (u16*)alloc(64ull * 1280 * 2);
  u16* vipb  = (u16*)alloc(64ull * 1280 * 2);

  const int ntot4 = (16384 * 1280 + 308 * 2048 + 64 * 2048) / 4;
  k_convert_all<<<(ntot4 + 255) / 256, 256, 0, stream>>>(hs, ehs, iph, hsb, ehsb, ipb);
  k_transpose4<<<dim3(40, 64, 4), 256, 0, stream>>>(Wk, Wv, Wkip, Wvip,
                                                    WkT, WvT, WkipT, WvipT, 2048, 1280);
  k_transpose2<<<dim3(40, 40, 2), 256, 0, stream>>>(Wq, Wo, WqT, WoT, 1280, 1280);

  // Q projection (scale 1/8 baked in): 64 x 4 = 256 blocks, 1/CU
  k_gemm256<0><<<256, 512, 0, stream>>>(hsb, WqT, 1280, 1280, 0.125f,
                                        qbuf, nullptr, nullptr, nullptr, 4);
  // K/V/Kip/Vip projections in one launch
  k_gemm_small4<<<dim3(10, 3, 4), 256, 0, stream>>>(ehsb, ipb, WkT, WvT, WkipT, WvipT,
                                                    kbuf, vbuf, kipb, vipb);

  // fused attention (main + IP). attn_out overwrites hsb.
  k_attn<<<dim3(32, 20, 4), 512, 0, stream>>>(qbuf, kbuf, vbuf, kipb, vipb, mask,
                                              hsb, ipout);

  // out = attn_out @ Wo + bo + ip_out
  k_gemm256<1><<<256, 512, 0, stream>>>(hsb, WoT, 1280, 1280, 1.f,
                                        nullptr, out, bo, ipout, 4);
}

// Round 9
// 265.077 us; speedup vs baseline: 1.0050x; 1.0012x over previous
//
#include <hip/hip_runtime.h>

typedef __attribute__((ext_vector_type(4))) float f32x4;
typedef __attribute__((ext_vector_type(8))) short s16x8;
typedef __attribute__((ext_vector_type(8))) __bf16 bf16x8;
typedef unsigned short u16;

__device__ __forceinline__ u16 f2b(float f) {
  union { float f; unsigned u; } x; x.f = f;
  unsigned r = x.u + 0x7fffu + ((x.u >> 16) & 1u);
  return (u16)(r >> 16);
}
__device__ __forceinline__ float b2f(u16 u) {
  union { unsigned u; float f; } x; x.u = ((unsigned)u) << 16;
  return x.f;
}
__device__ __forceinline__ void gld16(const void* g, void* l) {
  __builtin_amdgcn_global_load_lds(
      (const __attribute__((address_space(1))) unsigned int*)g,
      (__attribute__((address_space(3))) unsigned int*)l, 16, 0, 0);
}
__device__ __forceinline__ f32x4 mfma_bf16(s16x8 a, s16x8 b, f32x4 c) {
  return __builtin_amdgcn_mfma_f32_16x16x32_bf16(
      __builtin_bit_cast(bf16x8, a), __builtin_bit_cast(bf16x8, b), c, 0, 0, 0);
}

#define BAR() asm volatile("s_barrier" ::: "memory")

// ---------------- fused fp32->bf16 conversion (all three activations) ----------------
__global__ void k_convert_all(const float* __restrict__ hs, const float* __restrict__ ehs,
                              const float* __restrict__ iph,
                              u16* __restrict__ hsb, u16* __restrict__ ehsb,
                              u16* __restrict__ ipb) {
  const int n1 = 16384 * 1280 / 4, n2 = 308 * 2048 / 4, n3 = 64 * 2048 / 4;
  int i = blockIdx.x * blockDim.x + threadIdx.x;
  const float* src; u16* dst; int j = i;
  if (i < n1) { src = hs; dst = hsb; }
  else if (i < n1 + n2) { src = ehs; dst = ehsb; j = i - n1; }
  else if (i < n1 + n2 + n3) { src = iph; dst = ipb; j = i - n1 - n2; }
  else return;
  float4 v = ((const float4*)src)[j];
  ushort4 o;
  o.x = f2b(v.x); o.y = f2b(v.y); o.z = f2b(v.z); o.w = f2b(v.w);
  ((ushort4*)dst)[j] = o;
}

// ---------------- weight transpose: W [K][N] fp32 -> WT [N][K] bf16 ----------------
__device__ __forceinline__ void transpose_tile(const float* __restrict__ W,
                                               u16* __restrict__ WT, int K, int N) {
  __shared__ float tile[32][33];
  int n0 = blockIdx.x * 32, k0 = blockIdx.y * 32;
  int tx = threadIdx.x & 31, ty = threadIdx.x >> 5;
#pragma unroll
  for (int i = 0; i < 32; i += 8)
    tile[ty + i][tx] = W[(size_t)(k0 + ty + i) * N + n0 + tx];
  __syncthreads();
#pragma unroll
  for (int i = 0; i < 32; i += 8)
    WT[(size_t)(n0 + ty + i) * K + k0 + tx] = f2b(tile[tx][ty + i]);
}

__global__ void k_transpose4(const float* W0, const float* W1, const float* W2,
                             const float* W3, u16* T0, u16* T1, u16* T2, u16* T3,
                             int K, int N) {
  int z = blockIdx.z;
  const float* W = (z == 0) ? W0 : (z == 1) ? W1 : (z == 2) ? W2 : W3;
  u16* T = (z == 0) ? T0 : (z == 1) ? T1 : (z == 2) ? T2 : T3;
  transpose_tile(W, T, K, N);
}
__global__ void k_transpose2(const float* W0, const float* W1, u16* T0, u16* T1,
                             int K, int N) {
  int z = blockIdx.z;
  transpose_tile(z ? W1 : W0, z ? T1 : T0, K, N);
}

// ---------------- small-GEMM core (128x128 tile), for K/V projections ----------------
__device__ __forceinline__ void gemm_core0(
    const u16* __restrict__ A, const u16* __restrict__ BT,
    int M, int N, int K, u16* __restrict__ outb, int m0, int n0) {
  const int tid = threadIdx.x;
  const int l = tid & 63;
  const int w = tid >> 6;
  const int wr = w >> 1, wc = w & 1;
  __shared__ u16 As[128 * 32];
  __shared__ u16 Bs[128 * 32];
  f32x4 acc[4][4] = {};

  const int o0 = tid * 16;
  const int o1 = o0 + 4096;
  const int ra0 = o0 >> 6, ca0 = (o0 & 63) >> 1;
  const int ra1 = o1 >> 6, ca1 = (o1 & 63) >> 1;
  int ga0 = m0 + ra0; if (ga0 >= M) ga0 = M - 1;
  int ga1 = m0 + ra1; if (ga1 >= M) ga1 = M - 1;
  const u16* Ar0 = A + (size_t)ga0 * K + ca0;
  const u16* Ar1 = A + (size_t)ga1 * K + ca1;
  const u16* Br0 = BT + (size_t)(n0 + ra0) * K + ca0;
  const u16* Br1 = BT + (size_t)(n0 + ra1) * K + ca1;

  for (int k0 = 0; k0 < K; k0 += 32) {
    gld16(Ar0 + k0, &As[o0 >> 1]);
    gld16(Ar1 + k0, &As[o1 >> 1]);
    gld16(Br0 + k0, &Bs[o0 >> 1]);
    gld16(Br1 + k0, &Bs[o1 >> 1]);
    __syncthreads();
    s16x8 af[4], bfr[4];
#pragma unroll
    for (int mi = 0; mi < 4; ++mi)
      af[mi] = *(const s16x8*)&As[(wr * 64 + mi * 16 + (l & 15)) * 32 + (l >> 4) * 8];
#pragma unroll
    for (int ni = 0; ni < 4; ++ni)
      bfr[ni] = *(const s16x8*)&Bs[(wc * 64 + ni * 16 + (l & 15)) * 32 + (l >> 4) * 8];
#pragma unroll
    for (int mi = 0; mi < 4; ++mi)
#pragma unroll
      for (int ni = 0; ni < 4; ++ni)
        acc[mi][ni] = mfma_bf16(af[mi], bfr[ni], acc[mi][ni]);
    __syncthreads();
  }

#pragma unroll
  for (int mi = 0; mi < 4; ++mi) {
    const int mbase = m0 + wr * 64 + mi * 16 + (l >> 4) * 4;
#pragma unroll
    for (int ni = 0; ni < 4; ++ni) {
      const int ncol = n0 + wc * 64 + ni * 16 + (l & 15);
#pragma unroll
      for (int r = 0; r < 4; ++r) {
        int m = mbase + r;
        if (m < M) outb[(size_t)m * N + ncol] = f2b(acc[mi][ni][r]);
      }
    }
  }
}

// the four K/V projections in one launch (z selects)
__global__ __launch_bounds__(256) void k_gemm_small4(
    const u16* __restrict__ ehsb, const u16* __restrict__ ipb,
    const u16* __restrict__ WkT, const u16* __restrict__ WvT,
    const u16* __restrict__ WkipT, const u16* __restrict__ WvipT,
    u16* kbuf, u16* vbuf, u16* kipb, u16* vipb) {
  const int z = blockIdx.z;
  const int M = (z < 2) ? 308 : 64;
  const int m0 = blockIdx.y * 128;
  if (m0 >= M) return;
  const u16* A = (z < 2) ? ehsb : ipb;
  const u16* BT = (z == 0) ? WkT : (z == 1) ? WvT : (z == 2) ? WkipT : WvipT;
  u16* out = (z == 0) ? kbuf : (z == 1) ? vbuf : (z == 2) ? kipb : vipb;
  gemm_core0(A, BT, M, 1280, 2048, out, m0, blockIdx.x * 128);
}

// ---------------- big GEMM: 256x320 tile, BK=64, ring-2, IN-WAVE PIPELINED READS ----
// C[M,N] = A[M,K](bf16) * BT[N,K]^T.  M=16384, N=1280 (=4x320), K%64==0, KT=K/64.
// grid = exactly 256 blocks (1/CU). 8 waves 2(m)x4(n); wave tile 128x80; acc 160 VGPR.
// LDS 144KB = 2 ring slots x { A 256x64 (32KB) + B 320x64 (40KB) }.
// Tile body: 4 read clusters SP0..SP3 software-pipelined against 4 MFMA clusters
// via counted lgkmcnt (DS completes in order; sched_barrier(0) pins clusters and
// fences MFMA hoisting past inline-asm waits, rule #18):
//   issue SP0(9) SP1(4) | lgkm(4) MFMA0 | issue SP2(9) | lgkm(9) MFMA1 |
//   issue SP3(4)+STAGE(9 vm) | lgkm(4) MFMA2 | lgkm(0) MFMA3 | vmcnt(0) BAR
// Each read cluster has >=1 MFMA cluster (~780 cy) of cover -> LDS || MFMA overlap.
// Staging: uniform 9 gld16/thread (4 A + 5 B chunks), row=chunk>>3, slot=chunk&7,
// source col slot pre-permuted by ^(row&7); frag reads use slot^(lr&7) (rows are
// 128B = 8x16B slots; row&7 == lr&7 for all fragment rows). Both-sides swizzle.
template <int EPI>
__global__ __launch_bounds__(512, 1) void k_gemm256(
    const u16* __restrict__ A, const u16* __restrict__ BT,
    int N, int K, float alpha,
    u16* __restrict__ outb, float* __restrict__ outf,
    const float* __restrict__ bias, const u16* __restrict__ ipadd,
    int nbx) {
  __shared__ u16 lds[73728];  // slot s at s*36864: A [0,16384) u16, B [16384,36864)
  const int tid = threadIdx.x, l = tid & 63, w = tid >> 6;
  const int lr = l & 15, lg = l >> 4;
  const int wr = w >> 2, wc = w & 3;

  // bijective chunked XCD swizzle (T1); nwg=256 -> q=32, r=0
  const int nwg = gridDim.x;
  const int q = nwg >> 3, r = nwg & 7;
  const int xcd = blockIdx.x & 7, lid = blockIdx.x >> 3;
  const int wg = (xcd < r) ? (xcd * (q + 1) + lid)
                           : (r * (q + 1) + (xcd - r) * q + lid);
  const int bm0 = (wg / nbx) * 256, bn0 = (wg % nbx) * 320;

  // staging: thread covers rows (tid>>3)+64*i, dest 16B-slot tid&7; fixed src perm
  const int srow = tid >> 3;
  const int scol = ((tid & 7) ^ (srow & 7)) * 8;
  const int aOff0 = (bm0 + srow) * K + scol;
  const int bOff0 = (bn0 + srow) * K + scol;
  const int dD = tid * 8;

  const int KT = K >> 6;
  f32x4 acc[8][5] = {};

  // frag read slots: k-slot s = kk*4+lg, stored at s^(row&7), row&7 == lr&7
  const int xs0 = (lg ^ (lr & 7)) * 8;        // kk=0
  const int xs1 = ((4 + lg) ^ (lr & 7)) * 8;  // kk=1
  const int aR = (wr * 128 + lr) * 64;            // + mi*1024 (+ slot base)
  const int bR = 16384 + (wc * 80 + lr) * 64;     // + ni*1024 (+ slot base)

#define SB0() __builtin_amdgcn_sched_barrier(0)
#define LGKM(n) asm volatile("s_waitcnt lgkmcnt(" #n ")" ::: "memory")
#define VMW0() asm volatile("s_waitcnt vmcnt(0)" ::: "memory")
#define STAGE(slotu, kt)                                                \
  {                                                                     \
    const int sb_ = (slotu);                                            \
    const int ko_ = (kt) * 64;                                          \
    _Pragma("unroll")                                                   \
    for (int i_ = 0; i_ < 4; ++i_)                                      \
      gld16(A + aOff0 + i_ * 64 * K + ko_, &lds[sb_ + dD + i_ * 4096]); \
    _Pragma("unroll")                                                   \
    for (int i_ = 0; i_ < 5; ++i_)                                      \
      gld16(BT + bOff0 + i_ * 64 * K + ko_,                             \
            &lds[sb_ + 16384 + dD + i_ * 4096]);                        \
  }

  // prologue: stage tile 0 into slot 0
  STAGE(0, 0);
  VMW0();
  BAR();

  s16x8 afvA[4], afvB[4], bfvA[5], bfvB[5];
  for (int j = 0; j < KT; ++j) {
    const int sb = (j & 1) * 36864;
    const int nsb = 36864 - sb;
    const bool pf = (j + 1 < KT);
    // SP0: A[kk0, mi0-3] + B[kk0]
#pragma unroll
    for (int mi = 0; mi < 4; ++mi)
      afvA[mi] = *(const s16x8*)&lds[sb + aR + mi * 1024 + xs0];
#pragma unroll
    for (int ni = 0; ni < 5; ++ni)
      bfvA[ni] = *(const s16x8*)&lds[sb + bR + ni * 1024 + xs0];
    SB0();
    // SP1: A[kk0, mi4-7]
#pragma unroll
    for (int mi = 0; mi < 4; ++mi)
      afvB[mi] = *(const s16x8*)&lds[sb + aR + (mi + 4) * 1024 + xs0];
    SB0();
    LGKM(4); SB0();  // SP0 landed (SP1's 4 may be outstanding)
    __builtin_amdgcn_s_setprio(1);
#pragma unroll
    for (int mi = 0; mi < 4; ++mi)
#pragma unroll
      for (int ni = 0; ni < 5; ++ni)
        acc[mi][ni] = mfma_bf16(afvA[mi], bfvA[ni], acc[mi][ni]);
    __builtin_amdgcn_s_setprio(0);
    SB0();
    // SP2: A[kk1, mi0-3] + B[kk1]   (reads overlap MFMA0 above / MFMA1 below)
#pragma unroll
    for (int mi = 0; mi < 4; ++mi)
      afvA[mi] = *(const s16x8*)&lds[sb + aR + mi * 1024 + xs1];
#pragma unroll
    for (int ni = 0; ni < 5; ++ni)
      bfvB[ni] = *(const s16x8*)&lds[sb + bR + ni * 1024 + xs1];
    SB0();
    LGKM(9); SB0();  // SP1 landed (SP2's 9 may be outstanding)
    __builtin_amdgcn_s_setprio(1);
#pragma unroll
    for (int mi = 0; mi < 4; ++mi)
#pragma unroll
      for (int ni = 0; ni < 5; ++ni)
        acc[mi + 4][ni] = mfma_bf16(afvB[mi], bfvA[ni], acc[mi + 4][ni]);
    __builtin_amdgcn_s_setprio(0);
    SB0();
    // SP3: A[kk1, mi4-7] + stage next tile (vm, doesn't touch lgkm)
#pragma unroll
    for (int mi = 0; mi < 4; ++mi)
      afvB[mi] = *(const s16x8*)&lds[sb + aR + (mi + 4) * 1024 + xs1];
    SB0();
    if (pf) STAGE(nsb, j + 1);
    SB0();
    LGKM(4); SB0();  // SP2 landed (SP3's 4 may be outstanding)
    __builtin_amdgcn_s_setprio(1);
#pragma unroll
    for (int mi = 0; mi < 4; ++mi)
#pragma unroll
      for (int ni = 0; ni < 5; ++ni)
        acc[mi][ni] = mfma_bf16(afvA[mi], bfvB[ni], acc[mi][ni]);
    __builtin_amdgcn_s_setprio(0);
    SB0();
    LGKM(0); SB0();  // SP3 landed
    __builtin_amdgcn_s_setprio(1);
#pragma unroll
    for (int mi = 0; mi < 4; ++mi)
#pragma unroll
      for (int ni = 0; ni < 5; ++ni)
        acc[mi + 4][ni] = mfma_bf16(afvB[mi], bfvB[ni], acc[mi + 4][ni]);
    __builtin_amdgcn_s_setprio(0);
    if (pf) VMW0();  // drain this tile's stage (covered by MFMA2+MFMA3)
    BAR();
  }

  __syncthreads();

  if constexpr (EPI == 0) {
    // repack through LDS in two 128-row halves -> full-line bf16 stores
#pragma unroll
    for (int half = 0; half < 2; ++half) {
      if (half) __syncthreads();
      if (wr == half) {
#pragma unroll
        for (int mi = 0; mi < 8; ++mi) {
          const int row = mi * 16 + lg * 4;
#pragma unroll
          for (int ni = 0; ni < 5; ++ni) {
            const int col = wc * 80 + ni * 16 + lr;
#pragma unroll
            for (int rr = 0; rr < 4; ++rr)
              lds[(row + rr) * 320 + col] = f2b(acc[mi][ni][rr] * alpha);
          }
        }
      }
      __syncthreads();
      // full-line stores: 8 lanes cover 128B contiguous of ONE row
      const int rbase = tid >> 3;  // 0..63
      const int cseg = tid & 7;    // 0..7
#pragma unroll
      for (int rr2 = 0; rr2 < 2; ++rr2)
#pragma unroll
        for (int jj = 0; jj < 5; ++jj) {
          const int row = rr2 * 64 + rbase;
          const int ch = cseg + jj * 8;  // 0..39
          *(int4*)(outb + (size_t)(bm0 + half * 128 + row) * N + bn0 + ch * 8) =
              *(const int4*)&lds[row * 320 + ch * 8];
        }
    }
  } else {
#pragma unroll
    for (int mi = 0; mi < 8; ++mi) {
      const int mrow = bm0 + wr * 128 + mi * 16 + lg * 4;
#pragma unroll
      for (int ni = 0; ni < 5; ++ni) {
        const int ncol = bn0 + wc * 80 + ni * 16 + lr;
#pragma unroll
        for (int rr = 0; rr < 4; ++rr) {
          const size_t idx = (size_t)(mrow + rr) * N + ncol;
          outf[idx] = acc[mi][ni][rr] + bias[ncol] + b2f(ipadd[idx]);
        }
      }
    }
  }
#undef SB0
#undef LGKM
#undef VMW0
#undef STAGE
}

// ---------------- fused attention (main + IP stream) ----------------
// grid (32, 20, 4), 512 threads = 8 waves, 128 q-rows/block, 16 rows/wave.
// KV arena rows: 0..76 K, 77..79 zero, 80..95 Kip, 96..172 V, 173..175 zero,
// 176..191 Vip. Segment-XOR swizzle: 16B segment s of row stored at s^((row>>3)&3).
__global__ __launch_bounds__(512, 4) void k_attn(
    const u16* __restrict__ Q,    // [16384][1280], pre-scaled by 1/8
    const u16* __restrict__ Kb,   // [308][1280]
    const u16* __restrict__ Vb,
    const u16* __restrict__ Kip,  // [64][1280]
    const u16* __restrict__ Vip,
    const float* __restrict__ mask,  // [4096][77]
    u16* __restrict__ Oattn,      // [16384][1280] bf16
    u16* __restrict__ Oip) {
  const int qt = blockIdx.x, h = blockIdx.y, b = blockIdx.z;
  const int tid = threadIdx.x, l = tid & 63, w = tid >> 6;
  const int lr = l & 15, lg = l >> 4;
  const int r0 = w * 16;
  const int m0 = b * 4096 + qt * 128;

  __shared__ u16 KV[192][72];
  __shared__ u16 Ps[128][104];
  __shared__ u16 P2s[128][40];

  const u16* qrow = Q + (size_t)(m0 + r0 + lr) * 1280 + h * 64;
  s16x8 aq0 = *(const s16x8*)(qrow + lg * 8);
  s16x8 aq1 = *(const s16x8*)(qrow + 32 + lg * 8);

  for (int s = tid; s < 192 * 8; s += 512) {
    const int row = s >> 3, seg = s & 7;
    int4 v = {0, 0, 0, 0};
    const u16* src = nullptr;
    if (row < 77)       src = Kb  + (size_t)(b * 77 + row) * 1280 + h * 64 + seg * 8;
    else if (row < 80)  src = nullptr;
    else if (row < 96)  src = Kip + (size_t)(b * 16 + row - 80) * 1280 + h * 64 + seg * 8;
    else if (row < 173) src = Vb  + (size_t)(b * 77 + row - 96) * 1280 + h * 64 + seg * 8;
    else if (row < 176) src = nullptr;
    else                src = Vip + (size_t)(b * 16 + row - 176) * 1280 + h * 64 + seg * 8;
    if (src) v = *(const int4*)src;
    *(int4*)&KV[row][(seg ^ ((row >> 3) & 3)) * 8] = v;
  }
  __syncthreads();

  f32x4 sc[5];
  f32x4 sip = {};
#pragma unroll
  for (int t5 = 0; t5 < 6; ++t5) {
    const int trow = t5 * 16 + lr;
    const int qz = (trow >> 3) & 3;
    s16x8 b0 = *(const s16x8*)&KV[trow][(lg ^ qz) * 8];
    s16x8 b1 = *(const s16x8*)&KV[trow][((lg + 4) ^ qz) * 8];
    f32x4 c = {};
    c = mfma_bf16(aq0, b0, c);
    c = mfma_bf16(aq1, b1, c);
    if (t5 < 5) sc[t5] = c; else sip = c;
  }

#pragma unroll
  for (int r = 0; r < 4; ++r) {
    float mx = fmaxf(fmaxf(fmaxf(sc[0][r], sc[1][r]), fmaxf(sc[2][r], sc[3][r])), sc[4][r]);
    mx = fmaxf(mx, __shfl_xor(mx, 1));
    mx = fmaxf(mx, __shfl_xor(mx, 2));
    mx = fmaxf(mx, __shfl_xor(mx, 4));
    mx = fmaxf(mx, __shfl_xor(mx, 8));
    float p[5], sm = 0.f;
#pragma unroll
    for (int t5 = 0; t5 < 5; ++t5) {
      bool valid = (t5 < 4) | (lr < 13);
      p[t5] = valid ? __expf(sc[t5][r] - mx) : 0.f;
      sm += p[t5];
    }
    sm += __shfl_xor(sm, 1);
    sm += __shfl_xor(sm, 2);
    sm += __shfl_xor(sm, 4);
    sm += __shfl_xor(sm, 8);
    const float inv = 1.0f / sm;
    const int row = r0 + lg * 4 + r;
    const int qg = qt * 128 + row;
#pragma unroll
    for (int t5 = 0; t5 < 5; ++t5) {
      int t = t5 * 16 + lr;
      float pf = 0.f;
      if (t < 77) pf = p[t5] * inv * mask[qg * 77 + t];
      Ps[row][t] = f2b(pf);
    }
    Ps[row][80 + lr] = 0;

    float m2 = sip[r];
    m2 = fmaxf(m2, __shfl_xor(m2, 1));
    m2 = fmaxf(m2, __shfl_xor(m2, 2));
    m2 = fmaxf(m2, __shfl_xor(m2, 4));
    m2 = fmaxf(m2, __shfl_xor(m2, 8));
    float pi = __expf(sip[r] - m2);
    float s2 = pi;
    s2 += __shfl_xor(s2, 1);
    s2 += __shfl_xor(s2, 2);
    s2 += __shfl_xor(s2, 4);
    s2 += __shfl_xor(s2, 8);
    P2s[row][lr] = 0;
    P2s[row][16 + lr] = f2b(pi / s2);
  }

  s16x8 ap[3];
#pragma unroll
  for (int ks = 0; ks < 3; ++ks)
    ap[ks] = *(const s16x8*)&Ps[r0 + lr][ks * 32 + lg * 8];
  s16x8 aip = *(const s16x8*)&P2s[r0 + lr][lg * 8];

  f32x4 om[4], oi[4];
#pragma unroll
  for (int nt = 0; nt < 4; ++nt) {
    const int dcol = (nt * 16 + lr) ^ (lg << 3);
    f32x4 o = {};
#pragma unroll
    for (int ks = 0; ks < 3; ++ks) {
      s16x8 bv;
#pragma unroll
      for (int j = 0; j < 8; ++j)
        bv[j] = (short)KV[96 + ks * 32 + lg * 8 + j][dcol];
      o = mfma_bf16(ap[ks], bv, o);
    }
    s16x8 bip;
#pragma unroll
    for (int j = 0; j < 8; ++j)
      bip[j] = (short)KV[160 + lg * 8 + j][dcol];
    f32x4 o2 = {};
    o2 = mfma_bf16(aip, bip, o2);
    om[nt] = o;
    oi[nt] = o2;
  }

  __syncthreads();

  u16 (*Om)[72] = (u16(*)[72]) & KV[0][0];
  u16 (*Oi)[72] = (u16(*)[72]) & Ps[0][0];
#pragma unroll
  for (int nt = 0; nt < 4; ++nt)
#pragma unroll
    for (int r = 0; r < 4; ++r) {
      const int row = r0 + lg * 4 + r;
      const int d = nt * 16 + lr;
      Om[row][d] = f2b(om[nt][r]);
      Oi[row][d] = f2b(oi[nt][r]);
    }
  __syncthreads();

  for (int s = tid; s < 128 * 8; s += 512) {
    const int row = s >> 3, seg = s & 7;
    const size_t g = (size_t)(m0 + row) * 1280 + h * 64 + seg * 8;
    *(int4*)(Oattn + g) = *(const int4*)&Om[row][seg * 8];
    *(int4*)(Oip + g) = *(const int4*)&Oi[row][seg * 8];
  }
}

// ---------------- launch ----------------
extern "C" void kernel_launch(void* const* d_in, const int* in_sizes, int n_in,
                              void* d_out, int out_size, void* d_ws, size_t ws_size,
                              hipStream_t stream) {
  (void)in_sizes; (void)n_in; (void)out_size; (void)ws_size;
  const float* hs   = (const float*)d_in[0];
  const float* ehs  = (const float*)d_in[1];
  const float* iph  = (const float*)d_in[2];
  const float* mask = (const float*)d_in[3];
  const float* Wq   = (const float*)d_in[4];
  const float* Wk   = (const float*)d_in[5];
  const float* Wv   = (const float*)d_in[6];
  const float* Wo   = (const float*)d_in[7];
  const float* bo   = (const float*)d_in[8];
  const float* Wkip = (const float*)d_in[9];
  const float* Wvip = (const float*)d_in[10];
  float* out = (float*)d_out;

  char* ws = (char*)d_ws;
  size_t off = 0;
  auto alloc = [&](size_t bytes) {
    char* p = ws + off;
    off += (bytes + 255) & ~(size_t)255;
    return p;
  };
  u16* hsb   = (u16*)alloc(16384ull * 1280 * 2);  // reused as attn_out
  u16* qbuf  = (u16*)alloc(16384ull * 1280 * 2);
  u16* ipout = (u16*)alloc(16384ull * 1280 * 2);
  u16* WqT   = (u16*)alloc(1280ull * 1280 * 2);
  u16* WoT   = (u16*)alloc(1280ull * 1280 * 2);
  u16* WkT   = (u16*)alloc(1280ull * 2048 * 2);
  u16* WvT   = (u16*)alloc(1280ull * 2048 * 2);
  u16* WkipT = (u16*)alloc(1280ull * 2048 * 2);
  u16* WvipT = (u16*)alloc(1280ull * 2048 * 2);
  u16* ehsb  = (u16*)alloc(308ull * 2048 * 2);
  u16* ipb   = (u16*)alloc(64ull * 2048 * 2);
  u16* kbuf  = (u16*)alloc(308ull * 1280 * 2);
  u16* vbuf  = (u16*)alloc(308ull * 1280 * 2);
  u16* kipb  = (u16*)alloc(64ull * 1280 * 2);
  u16* vipb  = (u16*)alloc(64ull * 1280 * 2);

  const int ntot4 = (16384 * 1280 + 308 * 2048 + 64 * 2048) / 4;
  k_convert_all<<<(ntot4 + 255) / 256, 256, 0, stream>>>(hs, ehs, iph, hsb, ehsb, ipb);
  k_transpose4<<<dim3(40, 64, 4), 256, 0, stream>>>(Wk, Wv, Wkip, Wvip,
                                                    WkT, WvT, WkipT, WvipT, 2048, 1280);
  k_transpose2<<<dim3(40, 40, 2), 256, 0, stream>>>(Wq, Wo, WqT, WoT, 1280, 1280);

  // Q projection (scale 1/8 baked in): 64 x 4 = 256 blocks, 1/CU
  k_gemm256<0><<<256, 512, 0, stream>>>(hsb, WqT, 1280, 1280, 0.125f,
                                        qbuf, nullptr, nullptr, nullptr, 4);
  // K/V/Kip/Vip projections in one launch
  k_gemm_small4<<<dim3(10, 3, 4), 256, 0, stream>>>(ehsb, ipb, WkT, WvT, WkipT, WvipT,
                                                    kbuf, vbuf, kipb, vipb);

  // fused attention (main + IP). attn_out overwrites hsb.
  k_attn<<<dim3(32, 20, 4), 512, 0, stream>>>(qbuf, kbuf, vbuf, kipb, vipb, mask,
                                              hsb, ipout);

  // out = attn_out @ Wo + bo + ip_out
  k_gemm256<1><<<256, 512, 0, stream>>>(hsb, WoT, 1280, 1280, 1.f,
                                        nullptr, out, bo, ipout, 4);
}